// Round 12
// baseline (133.458 us; speedup 1.0000x reference)
//
#include <hip/hip_runtime.h>
#include <stdint.h>

#define NB 32
#define NT 2000
#define NH 256
#define NS 63
#define LDSROW 264   // padded bf16 row stride (528 B)

typedef __attribute__((ext_vector_type(8))) short bf16x8;
typedef __attribute__((ext_vector_type(4))) float f32x4;

__device__ inline unsigned short f2bf(float f) {
  union { float f; uint32_t u; } v; v.f = f;
  return (unsigned short)((v.u + 0x7fffu + ((v.u >> 16) & 1u)) >> 16);  // RNE
}
__device__ inline unsigned int pk2(float a, float b) {
  return (unsigned int)f2bf(a) | ((unsigned int)f2bf(b) << 16);
}
__device__ inline bf16x8 pack8(const float* g) {
  union { bf16x8 v; unsigned int u[4]; } c;
  c.u[0] = pk2(g[0], g[1]); c.u[1] = pk2(g[2], g[3]);
  c.u[2] = pk2(g[4], g[5]); c.u[3] = pk2(g[6], g[7]);
  return c.v;
}

// HW packed f32->bf16 (RNE, identical to f2bf for normal values).
__device__ inline unsigned int pk2_hw(float a, float b) {
  unsigned int r;
  asm("v_cvt_pk_bf16_f32 %0, %1, %2" : "=v"(r) : "v"(a), "v"(b));
  return r;
}
__device__ inline unsigned short cvt1_hw(float a) {
  unsigned int r;
  asm("v_cvt_pk_bf16_f32 %0, %1, %1" : "=v"(r) : "v"(a));
  return (unsigned short)r;
}

// Pre-packed MFMA B-fragment layouts (bf16), built once per launch in d_ws:
//   W1F: [km:16][c:4][tn:4][lane:64][j:8]  -> 16384 slots * 16 B = 256 KiB
//   W2F: [ks:8][tn:4][lane:64][j:8]        ->  2048 slots * 16 B =  32 KiB
#define NSLOT1 (16 * 4 * 4 * 64)
#define NSLOT2 (8 * 4 * 64)
#define WS_NEEDED ((size_t)(NSLOT1 + NSLOT2) * 16)

__global__ __launch_bounds__(256) void prep_weights(
    const float* __restrict__ W1, const float* __restrict__ W2,
    unsigned short* __restrict__ w1f, unsigned short* __restrict__ w2f) {
  const int tid = blockIdx.x * 256 + threadIdx.x;
  if (tid < NSLOT1) {
    const int lane = tid & 63;
    const int quad = lane >> 4, l16 = lane & 15;
    int r = tid >> 6;
    const int tn = r & 3; r >>= 2;
    const int wv = r & 3; r >>= 2;
    const int km = r;  // 0..15
    const int kb = (km >> 3) * 256 + (km & 7) * 32 + quad * 8;
    const int n = wv * 64 + tn * 16 + l16;
    ushort4 lo, hi;
    lo.x = f2bf(W1[(size_t)(kb + 0) * NH + n]);
    lo.y = f2bf(W1[(size_t)(kb + 1) * NH + n]);
    lo.z = f2bf(W1[(size_t)(kb + 2) * NH + n]);
    lo.w = f2bf(W1[(size_t)(kb + 3) * NH + n]);
    hi.x = f2bf(W1[(size_t)(kb + 4) * NH + n]);
    hi.y = f2bf(W1[(size_t)(kb + 5) * NH + n]);
    hi.z = f2bf(W1[(size_t)(kb + 6) * NH + n]);
    hi.w = f2bf(W1[(size_t)(kb + 7) * NH + n]);
    *(ushort4*)&w1f[(size_t)tid * 8] = lo;
    *(ushort4*)&w1f[(size_t)tid * 8 + 4] = hi;
  } else if (tid < NSLOT1 + NSLOT2) {
    const int t2 = tid - NSLOT1;
    const int lane = t2 & 63;
    const int quad = lane >> 4, l16 = lane & 15;
    const int tn = (t2 >> 6) & 3;
    const int ks = t2 >> 8;  // 0..7
    const int kb = ks * 32 + quad * 8;
    const int n = tn * 16 + l16;
    ushort4 lo = {0, 0, 0, 0}, hi = {0, 0, 0, 0};
    if (n < NS) {
      lo.x = f2bf(W2[(size_t)(kb + 0) * NS + n]);
      lo.y = f2bf(W2[(size_t)(kb + 1) * NS + n]);
      lo.z = f2bf(W2[(size_t)(kb + 2) * NS + n]);
      lo.w = f2bf(W2[(size_t)(kb + 3) * NS + n]);
      hi.x = f2bf(W2[(size_t)(kb + 4) * NS + n]);
      hi.y = f2bf(W2[(size_t)(kb + 5) * NS + n]);
      hi.z = f2bf(W2[(size_t)(kb + 6) * NS + n]);
      hi.w = f2bf(W2[(size_t)(kb + 7) * NS + n]);
    }
    *(ushort4*)&w2f[(size_t)t2 * 8] = lo;
    *(ushort4*)&w2f[(size_t)t2 * 8 + 4] = hi;
  }
}

// R12 = R11 (41.3 us/dispatch: 256 threads, 64-row tile, 4 blocks/CU,
// 64 VGPR + 64 AGPR, wave-local U, batched softmax) + k-chunked stage:
// GEMM1's km and km+8 read the SAME E columns ((km&7)*32..+31), so the tile
// splits into column halves. Stage cols 0..127 only (half the synchronized
// HBM burst), run kms {0-3,8-11} while STREAMING cols 128..255 (one float4
// per thread per km, 1-deep in flight = 4 VGPR — not bulk, the R7/R9 spill
// killer), barrier, then kms {4-7,12-15} with the original B-prefetch.
// Sub-loop A drops the B-prefetch (frees 16 VGPR, stays under the 128-reg
// cliff); unroll-1 prevents the compiler hoisting stream loads into bulk.
// Accumulation-order change is ulp-level (tol 4e-3).
template <bool PACKED>
__global__ __launch_bounds__(256, 4) void fused_kernel(
    const float* __restrict__ E, const float* __restrict__ logits,
    const int* __restrict__ kw,
    const float* __restrict__ W1, const float* __restrict__ W2,
    const unsigned short* __restrict__ w1f, const unsigned short* __restrict__ w2f,
    const float* __restrict__ b1, const float* __restrict__ b2,
    float* __restrict__ out) {
  const int b = blockIdx.y;
  const int a0 = blockIdx.x * 63;   // first align t of this block
  const int base = a0 - 1;          // first trans row computed
  const int tid = threadIdx.x;
  const int w = tid >> 6;
  const int lane = tid & 63;
  const int quad = lane >> 4;
  const int l16 = lane & 15;
  const int n0 = w * 64;

  __shared__ unsigned short lds[65 * LDSROW];  // 34320 B: E-tile -> h -> U

  const float* Eb = E + (size_t)b * NT * NH;
  const float* lb = logits + (size_t)b * NT * NS;

  f32x4 acc[4][4];
  #pragma unroll
  for (int tm = 0; tm < 4; ++tm)
    #pragma unroll
    for (int tn = 0; tn < 4; ++tn) acc[tm][tn] = (f32x4){0.f, 0.f, 0.f, 0.f};

  if constexpr (PACKED) {
    // ---- stage HALF 0 (cols 0..127): 2 rows per wave-instruction ----
    const int r2 = lane >> 5;          // 0/1: which of the 2 rows
    const int cf = (lane & 31) << 2;   // f32-col 0..124
    #pragma unroll
    for (int it = 0; it < 8; ++it) {
      const int row = it * 8 + (w << 1) + r2;
      int tr = base + row;
      tr = (tr < 0) ? 0 : (tr > NT - 1 ? NT - 1 : tr);
      float4 v = *(const float4*)&Eb[(size_t)tr * NH + cf];
      uint2 o; o.x = pk2_hw(v.x, v.y); o.y = pk2_hw(v.z, v.w);
      *(uint2*)&lds[row * LDSROW + cf] = o;
    }
    if (tid < 32) {  // boundary row 64, cols 0..127
      int tr = base + 64; if (tr > NT - 1) tr = NT - 1;
      float4 v = *(const float4*)&Eb[(size_t)tr * NH + cf];
      uint2 o; o.x = pk2_hw(v.x, v.y); o.y = pk2_hw(v.z, v.w);
      *(uint2*)&lds[64 * LDSROW + cf] = o;
    }
    __syncthreads();  // B1: half 0 staged

    const unsigned short* wbase = w1f + (size_t)(((w << 2) * 64) + lane) * 8;
#define W1F_AT(KM, TN) \
  (*(const bf16x8*)(wbase + ((size_t)((((KM) << 4) + (TN))) << 9)))

    // ---- GEMM1 sub-loop A: km in {0-3,8-11} (cols 0..127), streaming
    //      half 1 (cols 128..255) one float4/thread/iter, 1-deep. ----
    float4 sv;
    {
      const int row0 = (w << 1) + r2;
      int tr = base + row0;
      tr = (tr < 0) ? 0 : (tr > NT - 1 ? NT - 1 : tr);
      sv = *(const float4*)&Eb[(size_t)tr * NH + 128 + cf];
    }
    #pragma unroll 1
    for (int kk = 0; kk < 8; ++kk) {
      const int km = kk + ((kk >> 2) << 2);       // 0,1,2,3,8,9,10,11
      const int aoff = (km >> 3) ? 0 : 1;         // top half pairs e[t+1]
      bf16x8 cb0 = W1F_AT(km, 0), cb1 = W1F_AT(km, 1);
      bf16x8 cb2 = W1F_AT(km, 2), cb3 = W1F_AT(km, 3);
      bf16x8 af[4];
      #pragma unroll
      for (int tm = 0; tm < 4; ++tm)
        af[tm] = *(const bf16x8*)&lds[(tm * 16 + l16 + aoff) * LDSROW +
                                      (km & 7) * 32 + quad * 8];
      __builtin_amdgcn_s_setprio(1);
      #pragma unroll
      for (int tm = 0; tm < 4; ++tm)
        acc[tm][0] = __builtin_amdgcn_mfma_f32_16x16x32_bf16(af[tm], cb0, acc[tm][0], 0, 0, 0);
      #pragma unroll
      for (int tm = 0; tm < 4; ++tm)
        acc[tm][1] = __builtin_amdgcn_mfma_f32_16x16x32_bf16(af[tm], cb1, acc[tm][1], 0, 0, 0);
      #pragma unroll
      for (int tm = 0; tm < 4; ++tm)
        acc[tm][2] = __builtin_amdgcn_mfma_f32_16x16x32_bf16(af[tm], cb2, acc[tm][2], 0, 0, 0);
      #pragma unroll
      for (int tm = 0; tm < 4; ++tm)
        acc[tm][3] = __builtin_amdgcn_mfma_f32_16x16x32_bf16(af[tm], cb3, acc[tm][3], 0, 0, 0);
      __builtin_amdgcn_s_setprio(0);
      // stream: write the in-flight slot, preload the next
      {
        const int row = kk * 8 + (w << 1) + r2;
        uint2 o; o.x = pk2_hw(sv.x, sv.y); o.y = pk2_hw(sv.z, sv.w);
        *(uint2*)&lds[row * LDSROW + 128 + cf] = o;
        if (kk < 7) {
          const int nrow = (kk + 1) * 8 + (w << 1) + r2;
          int tr = base + nrow;
          tr = (tr < 0) ? 0 : (tr > NT - 1 ? NT - 1 : tr);
          sv = *(const float4*)&Eb[(size_t)tr * NH + 128 + cf];
        }
      }
    }
    if (tid < 32) {  // boundary row 64, cols 128..255
      int tr = base + 64; if (tr > NT - 1) tr = NT - 1;
      float4 v = *(const float4*)&Eb[(size_t)tr * NH + 128 + cf];
      uint2 o; o.x = pk2_hw(v.x, v.y); o.y = pk2_hw(v.z, v.w);
      *(uint2*)&lds[64 * LDSROW + 128 + cf] = o;
    }
    __syncthreads();  // B1b: half 1 staged

    // ---- GEMM1 sub-loop B: km in {4-7,12-15} (cols 128..255), with the
    //      original 1-deep B-register double buffer. ----
    {
      bf16x8 cb0 = W1F_AT(4, 0), cb1 = W1F_AT(4, 1);
      bf16x8 cb2 = W1F_AT(4, 2), cb3 = W1F_AT(4, 3);
      __builtin_amdgcn_s_setprio(1);
      #pragma unroll
      for (int kk = 0; kk < 8; ++kk) {
        const int km = kk + 4 + ((kk >> 2) << 2);   // 4,5,6,7,12,13,14,15
        bf16x8 nb0, nb1, nb2, nb3;
        if (kk < 7) {
          const int kn = (kk + 1) + 4 + (((kk + 1) >> 2) << 2);
          nb0 = W1F_AT(kn, 0); nb1 = W1F_AT(kn, 1);
          nb2 = W1F_AT(kn, 2); nb3 = W1F_AT(kn, 3);
        }
        const int aoff = (km >> 3) ? 0 : 1;
        bf16x8 af[4];
        #pragma unroll
        for (int tm = 0; tm < 4; ++tm)
          af[tm] = *(const bf16x8*)&lds[(tm * 16 + l16 + aoff) * LDSROW +
                                        (km & 7) * 32 + quad * 8];
        #pragma unroll
        for (int tm = 0; tm < 4; ++tm)
          acc[tm][0] = __builtin_amdgcn_mfma_f32_16x16x32_bf16(af[tm], cb0, acc[tm][0], 0, 0, 0);
        #pragma unroll
        for (int tm = 0; tm < 4; ++tm)
          acc[tm][1] = __builtin_amdgcn_mfma_f32_16x16x32_bf16(af[tm], cb1, acc[tm][1], 0, 0, 0);
        #pragma unroll
        for (int tm = 0; tm < 4; ++tm)
          acc[tm][2] = __builtin_amdgcn_mfma_f32_16x16x32_bf16(af[tm], cb2, acc[tm][2], 0, 0, 0);
        #pragma unroll
        for (int tm = 0; tm < 4; ++tm)
          acc[tm][3] = __builtin_amdgcn_mfma_f32_16x16x32_bf16(af[tm], cb3, acc[tm][3], 0, 0, 0);
        if (kk < 7) { cb0 = nb0; cb1 = nb1; cb2 = nb2; cb3 = nb3; }
      }
      __builtin_amdgcn_s_setprio(0);
    }
#undef W1F_AT
  } else {
    // Fallback: original full stage + gather GEMM1 (R11 structure).
    #pragma unroll
    for (int it = 0; it < 16; ++it) {
      const int row = it * 4 + w;
      int tr = base + row;
      tr = (tr < 0) ? 0 : (tr > NT - 1 ? NT - 1 : tr);
      float4 v = *(const float4*)&Eb[(size_t)tr * NH + (lane << 2)];
      uint2 o;
      o.x = pk2_hw(v.x, v.y); o.y = pk2_hw(v.z, v.w);
      *(uint2*)&lds[row * LDSROW + (lane << 2)] = o;
    }
    if (tid < 64) {
      int tr = base + 64; if (tr > NT - 1) tr = NT - 1;
      float4 v = *(const float4*)&Eb[(size_t)tr * NH + (lane << 2)];
      uint2 o;
      o.x = pk2_hw(v.x, v.y); o.y = pk2_hw(v.z, v.w);
      *(uint2*)&lds[64 * LDSROW + (lane << 2)] = o;
    }
    __syncthreads();

    const float* w1p = W1 + (size_t)(quad * 8) * NH + n0 + l16;
    #pragma unroll
    for (int km = 0; km < 16; ++km) {
      const int hk = (km >> 3) * 256 + (km & 7) * 32;
      const int aoff = (km >> 3) ? 0 : 1;
      bf16x8 af[4];
      #pragma unroll
      for (int tm = 0; tm < 4; ++tm)
        af[tm] = *(const bf16x8*)&lds[(tm * 16 + l16 + aoff) * LDSROW +
                                      (km & 7) * 32 + quad * 8];
      float g[8], gn[8];
      #pragma unroll
      for (int j = 0; j < 8; ++j) g[j] = w1p[(size_t)(hk + j) * NH];
      #pragma unroll
      for (int tn = 0; tn < 4; ++tn) {
        if (tn < 3) {
          #pragma unroll
          for (int j = 0; j < 8; ++j)
            gn[j] = w1p[(size_t)(hk + j) * NH + (tn + 1) * 16];
        }
        bf16x8 bq = pack8(g);
        #pragma unroll
        for (int tm = 0; tm < 4; ++tm)
          acc[tm][tn] = __builtin_amdgcn_mfma_f32_16x16x32_bf16(
              af[tm], bq, acc[tm][tn], 0, 0, 0);
        if (tn < 3) {
          #pragma unroll
          for (int j = 0; j < 8; ++j) g[j] = gn[j];
        }
      }
    }
  }
  __syncthreads();  // B2: GEMM1 A-reads done

  // h = relu(acc + b1) -> bf16 LDS rows 0..63 (HW cvt, 1 op/value)
  #pragma unroll
  for (int tn = 0; tn < 4; ++tn) {
    float b1v = b1[n0 + tn * 16 + l16];
    #pragma unroll
    for (int tm = 0; tm < 4; ++tm)
      #pragma unroll
      for (int r = 0; r < 4; ++r) {
        float hv = fmaxf(acc[tm][tn][r] + b1v, 0.f);
        lds[(tm * 16 + quad * 4 + r) * LDSROW + n0 + tn * 16 + l16] = cvt1_hw(hv);
      }
  }
  __syncthreads();  // B3

  // Prefetch logits values for this wave's U rows into registers (latency
  // hides under GEMM2). lpv[tn*4+r] pairs with acc2[tn][r].
  const int m0 = w * 16;
  float lpv[16];
  #pragma unroll
  for (int tn = 0; tn < 4; ++tn) {
    const int s = tn * 16 + l16;
    const int cc = (s < NS) ? s : NS - 1;
    #pragma unroll
    for (int r = 0; r < 4; ++r) {
      int tt = a0 + m0 + quad * 4 + r;
      if (tt > NT - 1) tt = NT - 1;
      lpv[tn * 4 + r] = lb[(size_t)tt * NS + cc];
    }
  }

  // GEMM2: wave w -> trans rows m0..m0+15 (A-reads touch ONLY rows m0..m0+15)
  f32x4 acc2[4];
  #pragma unroll
  for (int tn = 0; tn < 4; ++tn) acc2[tn] = (f32x4){0.f, 0.f, 0.f, 0.f};

  if constexpr (PACKED) {
    const unsigned short* w2base = w2f + (size_t)lane * 8;
    __builtin_amdgcn_s_setprio(1);
    #pragma unroll
    for (int ks = 0; ks < 8; ++ks) {
      bf16x8 af = *(const bf16x8*)&lds[(m0 + l16) * LDSROW + ks * 32 + quad * 8];
      #pragma unroll
      for (int tn = 0; tn < 4; ++tn) {
        bf16x8 bq = *(const bf16x8*)(w2base + ((size_t)((ks << 2) + tn) << 9));
        acc2[tn] = __builtin_amdgcn_mfma_f32_16x16x32_bf16(af, bq, acc2[tn], 0, 0, 0);
      }
    }
    __builtin_amdgcn_s_setprio(0);
  } else {
    #pragma unroll
    for (int ks = 0; ks < 8; ++ks) {
      const int k0 = ks * 32;
      bf16x8 af = *(const bf16x8*)&lds[(m0 + l16) * LDSROW + k0 + quad * 8];
      #pragma unroll
      for (int tn = 0; tn < 4; ++tn) {
        const int n = tn * 16 + l16;
        float g[8];
        #pragma unroll
        for (int j = 0; j < 8; ++j)
          g[j] = (n < NS) ? W2[(size_t)(k0 + quad * 8 + j) * NS + n] : 0.f;
        bf16x8 bq = pack8(g);
        acc2[tn] = __builtin_amdgcn_mfma_f32_16x16x32_bf16(af, bq, acc2[tn], 0, 0, 0);
      }
    }
  }

  // Wave-local U (NO barrier: write depends on this wave's own A-reads via
  // acc2, and targets the same rows m0..m0+15 only this wave read).
  // Layout: [16][68] f32 at float offset m0*132 (row j -> (j&15)*68).
  {
    float* Uw = (float*)(lds + (size_t)m0 * LDSROW);
    #pragma unroll
    for (int tn = 0; tn < 4; ++tn) {
      const int s = tn * 16 + l16;
      const float b2v = (s < NS) ? b2[s] : 0.f;
      #pragma unroll
      for (int r = 0; r < 4; ++r)
        Uw[(quad * 4 + r) * 68 + s] = acc2[tn][r] + b2v + lpv[tn * 4 + r];
    }
  }
  __syncthreads();  // B4: U complete (softmax reads cross-wave rows)

  // Softmax, fully unrolled + batched: 16 rows/wave, 16 independent
  // shfl-xor reduction chains interleaved per butterfly level.
  // U row j at float offset (j>>4)*2112 + (j&15)*68  (2112 = 16*132).
  const float* Ur = (const float*)lds;
  if (a0 == 0 && w == 0) {  // t = 0 special case
    float v = (lane < NS) ? lb[lane] : -1e30f;  // logits row 0 from global
    float m = v;
    #pragma unroll
    for (int o = 32; o > 0; o >>= 1) m = fmaxf(m, __shfl_xor(m, o));
    float ee = (lane < NS) ? __expf(v - m) : 0.f;
    float ss = ee;
    #pragma unroll
    for (int o = 32; o > 0; o >>= 1) ss += __shfl_xor(ss, o);
    const float lse = m + __logf(ss);
    const float f00 = lb[kw[b * 32]] - lse;
    float sc = ((lane == 0) ? f00 : 0.f) + Ur[68 + lane];  // + U[1]
    float e = (lane < NS) ? __expf(sc) : 0.f;
    float s = e;
    #pragma unroll
    for (int o = 32; o > 0; o >>= 1) s += __shfl_xor(s, o);
    if (lane < NS)
      out[(size_t)b * NT * NS + lane] = e * __builtin_amdgcn_rcpf(s);
  }

  float ev[16], sm[16];
  #pragma unroll
  for (int rr = 0; rr < 16; ++rr) {
    const int j = m0 + rr;
    const int t = a0 + j;
    const bool valid = (j < 63) && (t < NT) && (t != 0);
    float u0 = valid ? Ur[(j >> 4) * 2112 + (j & 15) * 68 + lane] : 0.f;
    float u1 = (valid && t != NT - 1)
                   ? Ur[((j + 1) >> 4) * 2112 + ((j + 1) & 15) * 68 + lane]
                   : 0.f;
    ev[rr] = (valid && lane < NS) ? __expf(u0 + u1) : 0.f;
    sm[rr] = ev[rr];
  }
  #pragma unroll
  for (int o = 32; o > 0; o >>= 1) {
    #pragma unroll
    for (int rr = 0; rr < 16; ++rr) sm[rr] += __shfl_xor(sm[rr], o);
  }
  #pragma unroll
  for (int rr = 0; rr < 16; ++rr) {
    const int j = m0 + rr;
    const int t = a0 + j;
    const bool valid = (j < 63) && (t < NT) && (t != 0);
    if (valid && lane < NS)
      out[((size_t)b * NT + t) * NS + lane] = ev[rr] * __builtin_amdgcn_rcpf(sm[rr]);
  }
}

extern "C" void kernel_launch(void* const* d_in, const int* in_sizes, int n_in,
                              void* d_out, int out_size, void* d_ws, size_t ws_size,
                              hipStream_t stream) {
  const float* logits = (const float*)d_in[0];
  const float* E      = (const float*)d_in[1];
  const int*   kw     = (const int*)d_in[2];
  const float* W1     = (const float*)d_in[3];
  const float* b1     = (const float*)d_in[4];
  const float* W2     = (const float*)d_in[5];
  const float* b2     = (const float*)d_in[6];
  float* out = (float*)d_out;

  dim3 g(32, NB);  // 32 t-blocks (63 t's each) x 32 batches = 1024 blocks

  if (ws_size >= WS_NEEDED && d_ws != nullptr) {
    unsigned short* w1f = (unsigned short*)d_ws;
    unsigned short* w2f = w1f + (size_t)NSLOT1 * 8;
    prep_weights<<<dim3((NSLOT1 + NSLOT2) / 256), 256, 0, stream>>>(W1, W2, w1f, w2f);
    fused_kernel<true><<<g, 256, 0, stream>>>(E, logits, kw, W1, W2, w1f, w2f,
                                              b1, b2, out);
  } else {
    fused_kernel<false><<<g, 256, 0, stream>>>(E, logits, kw, W1, W2, nullptr,
                                               nullptr, b1, b2, out);
  }
}

// Round 13
// 132.737 us; speedup vs baseline: 1.0054x; 1.0054x over previous
//
#include <hip/hip_runtime.h>
#include <stdint.h>

#define NB 32
#define NT 2000
#define NH 256
#define NS 63
#define LDSROW 264   // padded bf16 row stride (528 B)

typedef __attribute__((ext_vector_type(8))) short bf16x8;
typedef __attribute__((ext_vector_type(4))) float f32x4;

__device__ inline unsigned short f2bf(float f) {
  union { float f; uint32_t u; } v; v.f = f;
  return (unsigned short)((v.u + 0x7fffu + ((v.u >> 16) & 1u)) >> 16);  // RNE
}
__device__ inline unsigned int pk2(float a, float b) {
  return (unsigned int)f2bf(a) | ((unsigned int)f2bf(b) << 16);
}
__device__ inline bf16x8 pack8(const float* g) {
  union { bf16x8 v; unsigned int u[4]; } c;
  c.u[0] = pk2(g[0], g[1]); c.u[1] = pk2(g[2], g[3]);
  c.u[2] = pk2(g[4], g[5]); c.u[3] = pk2(g[6], g[7]);
  return c.v;
}

// HW packed f32->bf16 (RNE, identical to f2bf for normal values).
__device__ inline unsigned int pk2_hw(float a, float b) {
  unsigned int r;
  asm("v_cvt_pk_bf16_f32 %0, %1, %2" : "=v"(r) : "v"(a), "v"(b));
  return r;
}
__device__ inline unsigned short cvt1_hw(float a) {
  unsigned int r;
  asm("v_cvt_pk_bf16_f32 %0, %1, %1" : "=v"(r) : "v"(a));
  return (unsigned short)r;
}

// Pre-packed MFMA B-fragment layouts (bf16), built once per launch in d_ws:
//   W1F: [km:16][c:4][tn:4][lane:64][j:8]  -> 16384 slots * 16 B = 256 KiB
//   W2F: [ks:8][tn:4][lane:64][j:8]        ->  2048 slots * 16 B =  32 KiB
#define NSLOT1 (16 * 4 * 4 * 64)
#define NSLOT2 (8 * 4 * 64)
#define WS_NEEDED ((size_t)(NSLOT1 + NSLOT2) * 16)

__global__ __launch_bounds__(256) void prep_weights(
    const float* __restrict__ W1, const float* __restrict__ W2,
    unsigned short* __restrict__ w1f, unsigned short* __restrict__ w2f) {
  const int tid = blockIdx.x * 256 + threadIdx.x;
  if (tid < NSLOT1) {
    const int lane = tid & 63;
    const int quad = lane >> 4, l16 = lane & 15;
    int r = tid >> 6;
    const int tn = r & 3; r >>= 2;
    const int wv = r & 3; r >>= 2;
    const int km = r;  // 0..15
    const int kb = (km >> 3) * 256 + (km & 7) * 32 + quad * 8;
    const int n = wv * 64 + tn * 16 + l16;
    ushort4 lo, hi;
    lo.x = f2bf(W1[(size_t)(kb + 0) * NH + n]);
    lo.y = f2bf(W1[(size_t)(kb + 1) * NH + n]);
    lo.z = f2bf(W1[(size_t)(kb + 2) * NH + n]);
    lo.w = f2bf(W1[(size_t)(kb + 3) * NH + n]);
    hi.x = f2bf(W1[(size_t)(kb + 4) * NH + n]);
    hi.y = f2bf(W1[(size_t)(kb + 5) * NH + n]);
    hi.z = f2bf(W1[(size_t)(kb + 6) * NH + n]);
    hi.w = f2bf(W1[(size_t)(kb + 7) * NH + n]);
    *(ushort4*)&w1f[(size_t)tid * 8] = lo;
    *(ushort4*)&w1f[(size_t)tid * 8 + 4] = hi;
  } else if (tid < NSLOT1 + NSLOT2) {
    const int t2 = tid - NSLOT1;
    const int lane = t2 & 63;
    const int quad = lane >> 4, l16 = lane & 15;
    const int tn = (t2 >> 6) & 3;
    const int ks = t2 >> 8;  // 0..7
    const int kb = ks * 32 + quad * 8;
    const int n = tn * 16 + l16;
    ushort4 lo = {0, 0, 0, 0}, hi = {0, 0, 0, 0};
    if (n < NS) {
      lo.x = f2bf(W2[(size_t)(kb + 0) * NS + n]);
      lo.y = f2bf(W2[(size_t)(kb + 1) * NS + n]);
      lo.z = f2bf(W2[(size_t)(kb + 2) * NS + n]);
      lo.w = f2bf(W2[(size_t)(kb + 3) * NS + n]);
      hi.x = f2bf(W2[(size_t)(kb + 4) * NS + n]);
      hi.y = f2bf(W2[(size_t)(kb + 5) * NS + n]);
      hi.z = f2bf(W2[(size_t)(kb + 6) * NS + n]);
      hi.w = f2bf(W2[(size_t)(kb + 7) * NS + n]);
    }
    *(ushort4*)&w2f[(size_t)t2 * 8] = lo;
    *(ushort4*)&w2f[(size_t)t2 * 8 + 4] = hi;
  }
}

// R13 = R11 verbatim (best measured: 41.3 us/dispatch, 133.43 us bench).
// 256 threads, 64-row tile, 4 blocks/CU, 64 VGPR + 64 AGPR (exactly the
// 4-waves/SIMD cliff), pre-packed B-fragments, setprio around MFMA,
// wave-local U (4 barriers), batched softmax. Structural plateau: any
// cross-phase register state spills (R3/R7/R9); smaller acc doubles
// B-traffic (R5); LDS caps blocks/CU at 4. This decomposition's floor.
template <bool PACKED>
__global__ __launch_bounds__(256, 4) void fused_kernel(
    const float* __restrict__ E, const float* __restrict__ logits,
    const int* __restrict__ kw,
    const float* __restrict__ W1, const float* __restrict__ W2,
    const unsigned short* __restrict__ w1f, const unsigned short* __restrict__ w2f,
    const float* __restrict__ b1, const float* __restrict__ b2,
    float* __restrict__ out) {
  const int b = blockIdx.y;
  const int a0 = blockIdx.x * 63;   // first align t of this block
  const int base = a0 - 1;          // first trans row computed
  const int tid = threadIdx.x;
  const int w = tid >> 6;
  const int lane = tid & 63;
  const int quad = lane >> 4;
  const int l16 = lane & 15;
  const int n0 = w * 64;

  __shared__ unsigned short lds[65 * LDSROW];  // 34320 B: E-tile -> h -> U

  const float* Eb = E + (size_t)b * NT * NH;
  const float* lb = logits + (size_t)b * NT * NS;

  // Stage E rows base..base+64 (clamped), f32 -> bf16 via v_cvt_pk.
  #pragma unroll
  for (int it = 0; it < 16; ++it) {
    const int row = it * 4 + w;
    int tr = base + row;
    tr = (tr < 0) ? 0 : (tr > NT - 1 ? NT - 1 : tr);
    float4 v = *(const float4*)&Eb[(size_t)tr * NH + (lane << 2)];
    uint2 o;
    o.x = pk2_hw(v.x, v.y); o.y = pk2_hw(v.z, v.w);
    *(uint2*)&lds[row * LDSROW + (lane << 2)] = o;
  }
  if (tid < 64) {
    int tr = base + 64; if (tr > NT - 1) tr = NT - 1;
    float4 v = *(const float4*)&Eb[(size_t)tr * NH + (lane << 2)];
    uint2 o;
    o.x = pk2_hw(v.x, v.y); o.y = pk2_hw(v.z, v.w);
    *(uint2*)&lds[64 * LDSROW + (lane << 2)] = o;
  }
  __syncthreads();  // B1

  // GEMM1: h[m][n] = e[base+m+1]@W1_top + e[base+m]@W1_bot  (m = 0..63,
  // wave w owns cols n0..n0+63)
  f32x4 acc[4][4];
  #pragma unroll
  for (int tm = 0; tm < 4; ++tm)
    #pragma unroll
    for (int tn = 0; tn < 4; ++tn) acc[tm][tn] = (f32x4){0.f, 0.f, 0.f, 0.f};

  if constexpr (PACKED) {
    // fragment (km,tn) lives at wbase + ((km<<4)+tn)*512 ushorts
    const unsigned short* wbase = w1f + (size_t)(((w << 2) * 64) + lane) * 8;
#define W1F_AT(KM, TN) \
  (*(const bf16x8*)(wbase + ((size_t)((((KM) << 4) + (TN))) << 9)))
    bf16x8 cb0 = W1F_AT(0, 0), cb1 = W1F_AT(0, 1);
    bf16x8 cb2 = W1F_AT(0, 2), cb3 = W1F_AT(0, 3);
    __builtin_amdgcn_s_setprio(1);  // T5: favor MFMA-phase wave on this SIMD
    #pragma unroll
    for (int km = 0; km < 16; ++km) {
      bf16x8 nb0, nb1, nb2, nb3;
      if (km < 15) {  // one-ahead register double buffer (hides L2 latency)
        nb0 = W1F_AT(km + 1, 0); nb1 = W1F_AT(km + 1, 1);
        nb2 = W1F_AT(km + 1, 2); nb3 = W1F_AT(km + 1, 3);
      }
      const int aoff = (km >> 3) ? 0 : 1;  // top half pairs e[t+1]
      bf16x8 af[4];
      #pragma unroll
      for (int tm = 0; tm < 4; ++tm)
        af[tm] = *(const bf16x8*)&lds[(tm * 16 + l16 + aoff) * LDSROW +
                                      (km & 7) * 32 + quad * 8];
      #pragma unroll
      for (int tm = 0; tm < 4; ++tm)
        acc[tm][0] = __builtin_amdgcn_mfma_f32_16x16x32_bf16(af[tm], cb0, acc[tm][0], 0, 0, 0);
      #pragma unroll
      for (int tm = 0; tm < 4; ++tm)
        acc[tm][1] = __builtin_amdgcn_mfma_f32_16x16x32_bf16(af[tm], cb1, acc[tm][1], 0, 0, 0);
      #pragma unroll
      for (int tm = 0; tm < 4; ++tm)
        acc[tm][2] = __builtin_amdgcn_mfma_f32_16x16x32_bf16(af[tm], cb2, acc[tm][2], 0, 0, 0);
      #pragma unroll
      for (int tm = 0; tm < 4; ++tm)
        acc[tm][3] = __builtin_amdgcn_mfma_f32_16x16x32_bf16(af[tm], cb3, acc[tm][3], 0, 0, 0);
      if (km < 15) { cb0 = nb0; cb1 = nb1; cb2 = nb2; cb3 = nb3; }
    }
    __builtin_amdgcn_s_setprio(0);
#undef W1F_AT
  } else {
    const float* w1p = W1 + (size_t)(quad * 8) * NH + n0 + l16;
    #pragma unroll
    for (int km = 0; km < 16; ++km) {
      const int hk = (km >> 3) * 256 + (km & 7) * 32;
      const int aoff = (km >> 3) ? 0 : 1;
      bf16x8 af[4];
      #pragma unroll
      for (int tm = 0; tm < 4; ++tm)
        af[tm] = *(const bf16x8*)&lds[(tm * 16 + l16 + aoff) * LDSROW +
                                      (km & 7) * 32 + quad * 8];
      float g[8], gn[8];
      #pragma unroll
      for (int j = 0; j < 8; ++j) g[j] = w1p[(size_t)(hk + j) * NH];
      #pragma unroll
      for (int tn = 0; tn < 4; ++tn) {
        if (tn < 3) {
          #pragma unroll
          for (int j = 0; j < 8; ++j)
            gn[j] = w1p[(size_t)(hk + j) * NH + (tn + 1) * 16];
        }
        bf16x8 bq = pack8(g);
        #pragma unroll
        for (int tm = 0; tm < 4; ++tm)
          acc[tm][tn] = __builtin_amdgcn_mfma_f32_16x16x32_bf16(
              af[tm], bq, acc[tm][tn], 0, 0, 0);
        if (tn < 3) {
          #pragma unroll
          for (int j = 0; j < 8; ++j) g[j] = gn[j];
        }
      }
    }
  }
  __syncthreads();  // B2: GEMM1 A-reads done

  // h = relu(acc + b1) -> bf16 LDS rows 0..63 (HW cvt, 1 op/value)
  #pragma unroll
  for (int tn = 0; tn < 4; ++tn) {
    float b1v = b1[n0 + tn * 16 + l16];
    #pragma unroll
    for (int tm = 0; tm < 4; ++tm)
      #pragma unroll
      for (int r = 0; r < 4; ++r) {
        float hv = fmaxf(acc[tm][tn][r] + b1v, 0.f);
        lds[(tm * 16 + quad * 4 + r) * LDSROW + n0 + tn * 16 + l16] = cvt1_hw(hv);
      }
  }
  __syncthreads();  // B3

  // Prefetch logits values for this wave's U rows into registers (latency
  // hides under GEMM2). lpv[tn*4+r] pairs with acc2[tn][r].
  const int m0 = w * 16;
  float lpv[16];
  #pragma unroll
  for (int tn = 0; tn < 4; ++tn) {
    const int s = tn * 16 + l16;
    const int cc = (s < NS) ? s : NS - 1;
    #pragma unroll
    for (int r = 0; r < 4; ++r) {
      int tt = a0 + m0 + quad * 4 + r;
      if (tt > NT - 1) tt = NT - 1;
      lpv[tn * 4 + r] = lb[(size_t)tt * NS + cc];
    }
  }

  // GEMM2: wave w -> trans rows m0..m0+15 (A-reads touch ONLY rows m0..m0+15)
  f32x4 acc2[4];
  #pragma unroll
  for (int tn = 0; tn < 4; ++tn) acc2[tn] = (f32x4){0.f, 0.f, 0.f, 0.f};

  if constexpr (PACKED) {
    const unsigned short* w2base = w2f + (size_t)lane * 8;
    __builtin_amdgcn_s_setprio(1);
    #pragma unroll
    for (int ks = 0; ks < 8; ++ks) {
      bf16x8 af = *(const bf16x8*)&lds[(m0 + l16) * LDSROW + ks * 32 + quad * 8];
      #pragma unroll
      for (int tn = 0; tn < 4; ++tn) {
        bf16x8 bq = *(const bf16x8*)(w2base + ((size_t)((ks << 2) + tn) << 9));
        acc2[tn] = __builtin_amdgcn_mfma_f32_16x16x32_bf16(af, bq, acc2[tn], 0, 0, 0);
      }
    }
    __builtin_amdgcn_s_setprio(0);
  } else {
    #pragma unroll
    for (int ks = 0; ks < 8; ++ks) {
      const int k0 = ks * 32;
      bf16x8 af = *(const bf16x8*)&lds[(m0 + l16) * LDSROW + k0 + quad * 8];
      #pragma unroll
      for (int tn = 0; tn < 4; ++tn) {
        const int n = tn * 16 + l16;
        float g[8];
        #pragma unroll
        for (int j = 0; j < 8; ++j)
          g[j] = (n < NS) ? W2[(size_t)(k0 + quad * 8 + j) * NS + n] : 0.f;
        bf16x8 bq = pack8(g);
        acc2[tn] = __builtin_amdgcn_mfma_f32_16x16x32_bf16(af, bq, acc2[tn], 0, 0, 0);
      }
    }
  }

  // Wave-local U (NO barrier: write depends on this wave's own A-reads via
  // acc2, and targets the same rows m0..m0+15 only this wave read).
  // Layout: [16][68] f32 at float offset m0*132 (row j -> (j&15)*68).
  {
    float* Uw = (float*)(lds + (size_t)m0 * LDSROW);
    #pragma unroll
    for (int tn = 0; tn < 4; ++tn) {
      const int s = tn * 16 + l16;
      const float b2v = (s < NS) ? b2[s] : 0.f;
      #pragma unroll
      for (int r = 0; r < 4; ++r)
        Uw[(quad * 4 + r) * 68 + s] = acc2[tn][r] + b2v + lpv[tn * 4 + r];
    }
  }
  __syncthreads();  // B4: U complete (softmax reads cross-wave rows)

  // Softmax, fully unrolled + batched: 16 rows/wave, 16 independent
  // shfl-xor reduction chains interleaved per butterfly level.
  // U row j at float offset (j>>4)*2112 + (j&15)*68  (2112 = 16*132).
  const float* Ur = (const float*)lds;
  if (a0 == 0 && w == 0) {  // t = 0 special case
    float v = (lane < NS) ? lb[lane] : -1e30f;  // logits row 0 from global
    float m = v;
    #pragma unroll
    for (int o = 32; o > 0; o >>= 1) m = fmaxf(m, __shfl_xor(m, o));
    float ee = (lane < NS) ? __expf(v - m) : 0.f;
    float ss = ee;
    #pragma unroll
    for (int o = 32; o > 0; o >>= 1) ss += __shfl_xor(ss, o);
    const float lse = m + __logf(ss);
    const float f00 = lb[kw[b * 32]] - lse;
    float sc = ((lane == 0) ? f00 : 0.f) + Ur[68 + lane];  // + U[1]
    float e = (lane < NS) ? __expf(sc) : 0.f;
    float s = e;
    #pragma unroll
    for (int o = 32; o > 0; o >>= 1) s += __shfl_xor(s, o);
    if (lane < NS)
      out[(size_t)b * NT * NS + lane] = e * __builtin_amdgcn_rcpf(s);
  }

  float ev[16], sm[16];
  #pragma unroll
  for (int rr = 0; rr < 16; ++rr) {
    const int j = m0 + rr;
    const int t = a0 + j;
    const bool valid = (j < 63) && (t < NT) && (t != 0);
    float u0 = valid ? Ur[(j >> 4) * 2112 + (j & 15) * 68 + lane] : 0.f;
    float u1 = (valid && t != NT - 1)
                   ? Ur[((j + 1) >> 4) * 2112 + ((j + 1) & 15) * 68 + lane]
                   : 0.f;
    ev[rr] = (valid && lane < NS) ? __expf(u0 + u1) : 0.f;
    sm[rr] = ev[rr];
  }
  #pragma unroll
  for (int o = 32; o > 0; o >>= 1) {
    #pragma unroll
    for (int rr = 0; rr < 16; ++rr) sm[rr] += __shfl_xor(sm[rr], o);
  }
  #pragma unroll
  for (int rr = 0; rr < 16; ++rr) {
    const int j = m0 + rr;
    const int t = a0 + j;
    const bool valid = (j < 63) && (t < NT) && (t != 0);
    if (valid && lane < NS)
      out[((size_t)b * NT + t) * NS + lane] = ev[rr] * __builtin_amdgcn_rcpf(sm[rr]);
  }
}

extern "C" void kernel_launch(void* const* d_in, const int* in_sizes, int n_in,
                              void* d_out, int out_size, void* d_ws, size_t ws_size,
                              hipStream_t stream) {
  const float* logits = (const float*)d_in[0];
  const float* E      = (const float*)d_in[1];
  const int*   kw     = (const int*)d_in[2];
  const float* W1     = (const float*)d_in[3];
  const float* b1     = (const float*)d_in[4];
  const float* W2     = (const float*)d_in[5];
  const float* b2     = (const float*)d_in[6];
  float* out = (float*)d_out;

  dim3 g(32, NB);  // 32 t-blocks (63 t's each) x 32 batches = 1024 blocks

  if (ws_size >= WS_NEEDED && d_ws != nullptr) {
    unsigned short* w1f = (unsigned short*)d_ws;
    unsigned short* w2f = w1f + (size_t)NSLOT1 * 8;
    prep_weights<<<dim3((NSLOT1 + NSLOT2) / 256), 256, 0, stream>>>(W1, W2, w1f, w2f);
    fused_kernel<true><<<g, 256, 0, stream>>>(E, logits, kw, W1, W2, w1f, w2f,
                                              b1, b2, out);
  } else {
    fused_kernel<false><<<g, 256, 0, stream>>>(E, logits, kw, W1, W2, nullptr,
                                               nullptr, b1, b2, out);
  }
}